// Round 1
// baseline (362.403 us; speedup 1.0000x reference)
//
#include <hip/hip_runtime.h>
#include <hip/hip_bf16.h>

#define NB 31
#define PD 64

typedef __attribute__((ext_vector_type(8))) short short8;
typedef __attribute__((ext_vector_type(16))) float f32x16;

__device__ __forceinline__ float gelu_f(float x) {
    // tanh-approx GELU: x * sigmoid(2*0.79788456*(x + 0.044715 x^3)); max abs err ~9e-4
    float u = x * (0.7978845608f + 0.0356774081f * x * x);
    float e = __expf(-2.0f * u);
    return x * __builtin_amdgcn_rcpf(1.0f + e);
}

__device__ __forceinline__ unsigned short f2bf(float f) {
    unsigned int u = __float_as_uint(f);
    unsigned int r = (u + 0x7FFFu + ((u >> 16) & 1u)) >> 16;
    return (unsigned short)r;
}

// Reorder W2 (OIHW, fp32) -> MFMA A-fragment order (bf16):
// W2r[g][oh][kk][lane][j], oc = oh*32 + (lane&31), tap = kk>>2,
// ic = (kk&3)*16 + (lane>>5)*8 + j   (k-global = ic + 64*tap)
__global__ void prep_w2(const float* __restrict__ W2, unsigned short* __restrict__ W2r) {
    int e = blockIdx.x * 256 + threadIdx.x;
    const int TOT = NB * 2 * 36 * 512;
    if (e >= TOT) return;
    int j  = e & 7;
    int l  = (e >> 3) & 63;
    int kk = (e >> 9) % 36;
    int gh = e / (36 * 512);
    int g  = gh >> 1, oh = gh & 1;
    int oc  = oh * 32 + (l & 31);
    int ic  = (kk & 3) * 16 + ((l >> 5) << 3) + j;
    int tap = kk >> 2;
    float v = W2[((g * 64 + oc) * 64 + ic) * 9 + tap];
    W2r[e] = f2bf(v);
}

// One block: (batch n, band g, 16x16 output tile). 256 threads = 4 waves.
// Fused: conv1+gelu -> LDS (bf16, swizzled) -> conv2 via mfma_32x32x16_bf16
//        -> gelu -> conv3 reduce -> processed written to `out`.
__global__ __launch_bounds__(256, 2) void band_kernel(
    const float* __restrict__ x, const float* __restrict__ W1, const float* __restrict__ b1,
    const float* __restrict__ b2, const float* __restrict__ W3, const float* __restrict__ b3,
    const unsigned short* __restrict__ W2r, float* __restrict__ out)
{
    __shared__ float  xs[20 * 20];
    __shared__ float  W1s[9 * 64];
    __shared__ float  b1s[64], b2s[64], W3s[64];
    __shared__ short8 h1s8[324 * 64 / 8];   // 41472 B, 16B aligned
    __shared__ float  out_s[2 * 256];

    const int tid = threadIdx.x;
    const int tx = blockIdx.x % 12, ty = blockIdx.x / 12;
    const int g = blockIdx.y, n = blockIdx.z;
    const int x0 = tx * 16, y0 = ty * 16;

    // ---- stage x tile (20x20, halo 2, zero-padded) ----
    const float* xg = x + (size_t)(n * NB + g) * 192 * 192;
    for (int i = tid; i < 400; i += 256) {
        int r = i / 20, c = i - r * 20;
        int gy = y0 + r - 2, gx = x0 + c - 2;
        float v = 0.f;
        if (gy >= 0 && gy < 192 && gx >= 0 && gx < 192) v = xg[gy * 192 + gx];
        xs[i] = v;
    }
    // ---- stage W1 (tap-major), biases, W3 ----
    for (int i = tid; i < 576; i += 256) {
        int tap = i >> 6, ic = i & 63;
        W1s[i] = W1[(g * 64 + ic) * 9 + tap];
    }
    if (tid < 64) {
        b1s[tid] = b1[g * 64 + tid];
        b2s[tid] = b2[g * 64 + tid];
        W3s[tid] = W3[g * 64 + tid];
    }
    __syncthreads();

    // ---- conv1 + gelu -> h1s (bf16, [pos][ic], XOR-swizzled) ----
    char* h1c = (char*)h1s8;
    for (int task = tid; task < 2592; task += 256) {
        int pos = task >> 3;
        int icb = (task & 7) << 3;
        int py = pos / 18, px = pos - py * 18;    // halo coords 0..17
        int gy = y0 + py - 1, gx = x0 + px - 1;
        short8 pack;
        if (gy >= 0 && gy < 192 && gx >= 0 && gx < 192) {
            float xv[9];
#pragma unroll
            for (int t = 0; t < 9; ++t) xv[t] = xs[(py + t / 3) * 20 + (px + t % 3)];
#pragma unroll
            for (int u = 0; u < 8; ++u) {
                float a = b1s[icb + u];
#pragma unroll
                for (int t = 0; t < 9; ++t) a += W1s[t * 64 + icb + u] * xv[t];
                pack[u] = (short)f2bf(gelu_f(a));
            }
        } else {
#pragma unroll
            for (int u = 0; u < 8; ++u) pack[u] = 0;  // conv2 zero-padding rows
        }
        int off = ((pos << 6) + icb) * 2;
        off ^= (pos & 7) << 4;
        *(short8*)(h1c + off) = pack;
    }
    __syncthreads();

    // ---- conv2 via MFMA: per wave: oc-half (w&1), px-half (w>>1) ----
    const int lane  = tid & 63;
    const int w     = tid >> 6;
    const int oh    = w & 1;
    const int ph    = w >> 1;
    const int lq    = lane >> 5;         // 0/1
    const int pxx   = lane & 15;
    const int lhalf = (lane >> 4) & 1;
    const int pyb   = ph * 8;            // base output row of this wave's px half

    const short8* aptr = (const short8*)W2r + ((size_t)(g * 2 + oh) * 36) * 64 + lane;
    f32x16 acc0 = {}, acc1 = {}, acc2 = {}, acc3 = {};

    short8 aA = aptr[0];
    short8 aB = aptr[64];
    for (int kk = 0; kk < 36; ++kk) {
        int pf = kk + 2; if (pf > 35) pf = 35;
        short8 aC = aptr[pf * 64];
        int tap = kk >> 2;
        int dy = tap / 3, dx = tap - dy * 3;          // 0..2
        int base = (pyb + lhalf + dy) * 18 + (pxx + dx);
        int icb2 = (((kk & 3) << 4) + (lq << 3)) << 1; // ic byte offset in row
#define MSTEP(NT, ACC)                                                        \
        {                                                                     \
            int pos = base + (NT) * 36;                                       \
            int off = ((pos << 7) + icb2) ^ ((pos & 7) << 4);                 \
            short8 bfr = *(const short8*)(h1c + off);                         \
            ACC = __builtin_amdgcn_mfma_f32_32x32x16_bf16(aA, bfr, ACC, 0, 0, 0); \
        }
        MSTEP(0, acc0) MSTEP(1, acc1) MSTEP(2, acc2) MSTEP(3, acc3)
#undef MSTEP
        aA = aB; aB = aC;
    }

    // ---- epilogue: gelu(+b2), conv3 dot W3, reduce, write processed ----
    const float b3g = b3[g];
#define EPI(NT, ACC)                                                          \
    {                                                                         \
        float p = 0.f;                                                        \
        _Pragma("unroll")                                                     \
        for (int r = 0; r < 16; ++r) {                                        \
            int ocl = (r & 3) + ((r >> 2) << 3) + (lq << 2);                  \
            int oc = oh * 32 + ocl;                                           \
            float h2 = gelu_f(ACC[r] + b2s[oc]);                              \
            p += W3s[oc] * h2;                                                \
        }                                                                     \
        p += __shfl_xor(p, 32);                                               \
        if (lane < 32) out_s[oh * 256 + ph * 128 + (NT) * 32 + lane] = p;     \
    }
    EPI(0, acc0) EPI(1, acc1) EPI(2, acc2) EPI(3, acc3)
#undef EPI
    __syncthreads();

    {
        int px = tid;
        float s = out_s[px] + out_s[256 + px] + b3g;
        int py = px >> 4, pc = px & 15;
        out[((size_t)(n * NB + g) * 192 + (y0 + py)) * 192 + (x0 + pc)] = s;
    }
}

// Cross-band fusion, in-place on `out` (each thread owns a full 31-channel pixel column).
__global__ __launch_bounds__(256) void fuse_kernel(
    const float* __restrict__ x,
    const float* __restrict__ Wf1, const float* __restrict__ bf1,
    const float* __restrict__ Wf2, const float* __restrict__ bf2,
    float* __restrict__ out)
{
    __shared__ float w1s[62 * 31], w2s[31 * 62], b1ss[62], b2ss[31];
    const int tid = threadIdx.x;
    for (int i = tid; i < 1922; i += 256) { w1s[i] = Wf1[i]; w2s[i] = Wf2[i]; }
    if (tid < 62) b1ss[tid] = bf1[tid];
    if (tid < 31) b2ss[tid] = bf2[tid];
    __syncthreads();

    int p = blockIdx.x * 256 + tid;          // 0..73727
    int nn = p / 36864, pix = p - nn * 36864;
    float* basep = out + (size_t)nn * NB * 36864 + pix;
    const float* xb = x + (size_t)nn * NB * 36864 + pix;

    float v[31];
#pragma unroll
    for (int c = 0; c < 31; ++c) v[c] = basep[(size_t)c * 36864];

    float fused[31];
#pragma unroll
    for (int c = 0; c < 31; ++c) fused[c] = b2ss[c];

    for (int j = 0; j < 62; ++j) {
        float a = b1ss[j];
#pragma unroll
        for (int c = 0; c < 31; ++c) a += w1s[j * 31 + c] * v[c];
        float fj = gelu_f(a);
#pragma unroll
        for (int c = 0; c < 31; ++c) fused[c] += w2s[c * 62 + j] * fj;
    }
#pragma unroll
    for (int c = 0; c < 31; ++c) basep[(size_t)c * 36864] = xb[(size_t)c * 36864] + fused[c];
}

extern "C" void kernel_launch(void* const* d_in, const int* in_sizes, int n_in,
                              void* d_out, int out_size, void* d_ws, size_t ws_size,
                              hipStream_t stream) {
    const float* x   = (const float*)d_in[0];
    const float* W1  = (const float*)d_in[1];
    const float* b1  = (const float*)d_in[2];
    const float* W2  = (const float*)d_in[3];
    const float* b2  = (const float*)d_in[4];
    const float* W3  = (const float*)d_in[5];
    const float* b3  = (const float*)d_in[6];
    const float* Wf1 = (const float*)d_in[7];
    const float* bf1 = (const float*)d_in[8];
    const float* Wf2 = (const float*)d_in[9];
    const float* bf2 = (const float*)d_in[10];
    float* out = (float*)d_out;
    unsigned short* W2r = (unsigned short*)d_ws;   // 1142784 bf16 = 2.29 MB

    const int TOT = NB * 2 * 36 * 512;
    hipLaunchKernelGGL(prep_w2, dim3((TOT + 255) / 256), dim3(256), 0, stream, W2, W2r);
    hipLaunchKernelGGL(band_kernel, dim3(144, NB, 2), dim3(256), 0, stream,
                       x, W1, b1, b2, W3, b3, W2r, out);
    hipLaunchKernelGGL(fuse_kernel, dim3(288), dim3(256), 0, stream,
                       x, Wf1, bf1, Wf2, bf2, out);
}

// Round 2
// 316.963 us; speedup vs baseline: 1.1434x; 1.1434x over previous
//
#include <hip/hip_runtime.h>
#include <hip/hip_bf16.h>

#define NB 31
#define PD 64

typedef __attribute__((ext_vector_type(8))) short short8;
typedef __attribute__((ext_vector_type(16))) float f32x16;

// 0-transcendental GELU: x * clamp(0.5 + x*(a + b x^2 + c x^4), 0, 1)
// odd-poly fit of Phi on [0,2.5]; |err| <= ~3e-3 in-range, clamps to exact tails.
__device__ __forceinline__ float gelu_f(float x) {
    float y = x * x;
    float p = __builtin_fmaf(y, __builtin_fmaf(y, 0.0042294f, -0.056913f), 0.395442f);
    float phi = __builtin_fmaf(x, p, 0.5f);
    phi = __builtin_fmaxf(0.0f, __builtin_fminf(phi, 1.0f));
    return x * phi;
}

__device__ __forceinline__ unsigned int cvt_pk_bf16(float lo, float hi) {
    unsigned int r;
    asm("v_cvt_pk_bf16_f32 %0, %1, %2" : "=v"(r) : "v"(lo), "v"(hi));
    return r;
}

__device__ __forceinline__ unsigned short f2bf(float f) {
    unsigned int u = __float_as_uint(f);
    unsigned int r = (u + 0x7FFFu + ((u >> 16) & 1u)) >> 16;
    return (unsigned short)r;
}

// Reorder W2 (OIHW, fp32) -> MFMA A-fragment order (bf16):
// W2r[g][oh][kk][lane][j], oc = oh*32 + (lane&31), tap = kk>>2,
// ic = (kk&3)*16 + (lane>>5)*8 + j
__global__ void prep_w2(const float* __restrict__ W2, unsigned short* __restrict__ W2r) {
    int e = blockIdx.x * 256 + threadIdx.x;
    const int TOT = NB * 2 * 36 * 512;
    if (e >= TOT) return;
    int j  = e & 7;
    int l  = (e >> 3) & 63;
    int kk = (e >> 9) % 36;
    int gh = e / (36 * 512);
    int g  = gh >> 1, oh = gh & 1;
    int oc  = oh * 32 + (l & 31);
    int ic  = (kk & 3) * 16 + ((l >> 5) << 3) + j;
    int tap = kk >> 2;
    float v = W2[((g * 64 + oc) * 64 + ic) * 9 + tap];
    W2r[e] = f2bf(v);
}

// One block: (batch n, band g, 16x16 output tile). 256 threads = 4 waves.
// Wave w owns px rows [4w,4w+4) x ALL 64 oc: each B-fragment read feeds 2 MFMAs.
__global__ __launch_bounds__(256, 3) void band_kernel(
    const float* __restrict__ x, const float* __restrict__ W1, const float* __restrict__ b1,
    const float* __restrict__ b2, const float* __restrict__ W3, const float* __restrict__ b3,
    const unsigned short* __restrict__ W2r, float* __restrict__ out)
{
    __shared__ float  xs[20 * 20];
    __shared__ float  W1s[9 * 64];
    __shared__ float  b1s[64], b2s[64], W3s[64];
    __shared__ short8 h1s8[324 * 8];   // 41472 B: [pos][64 ic] bf16, slot-swizzled

    const int tid = threadIdx.x;
    const int tx = blockIdx.x % 12, ty = blockIdx.x / 12;
    const int g = blockIdx.y, n = blockIdx.z;
    const int x0 = tx * 16, y0 = ty * 16;

    // ---- stage x tile (20x20, halo 2, zero-padded) ----
    const float* xg = x + (size_t)(n * NB + g) * 192 * 192;
    for (int i = tid; i < 400; i += 256) {
        int r = i / 20, c = i - r * 20;
        int gy = y0 + r - 2, gx = x0 + c - 2;
        float v = 0.f;
        if (gy >= 0 && gy < 192 && gx >= 0 && gx < 192) v = xg[gy * 192 + gx];
        xs[i] = v;
    }
    for (int i = tid; i < 576; i += 256) {
        int tap = i >> 6, ic = i & 63;
        W1s[i] = W1[(g * 64 + ic) * 9 + tap];
    }
    if (tid < 64) {
        b1s[tid] = b1[g * 64 + tid];
        b2s[tid] = b2[g * 64 + tid];
        W3s[tid] = W3[g * 64 + tid];
    }
    __syncthreads();

    // ---- conv1 + gelu -> h1s (bf16 [pos][ic], chunk^r slot swizzle) ----
    char* h1c = (char*)h1s8;
    for (int task = tid; task < 2592; task += 256) {
        int pos = task >> 3;
        int chunk = task & 7;                      // which 8-ic chunk
        int py = pos / 18, px = pos - py * 18;     // halo coords 0..17
        int gy = y0 + py - 1, gx = x0 + px - 1;
        int off = (pos << 7) + ((((pos & 7) ^ chunk)) << 4);
        uint4 pk = {0u, 0u, 0u, 0u};
        if (gy >= 0 && gy < 192 && gx >= 0 && gx < 192) {
            float xv[9];
#pragma unroll
            for (int t = 0; t < 9; ++t) xv[t] = xs[(py + t / 3) * 20 + (px + t % 3)];
            int icb = chunk << 3;
            float a[8];
#pragma unroll
            for (int u = 0; u < 8; ++u) {
                float s = b1s[icb + u];
#pragma unroll
                for (int t = 0; t < 9; ++t)
                    s = __builtin_fmaf(W1s[t * 64 + icb + u], xv[t], s);
                a[u] = gelu_f(s);
            }
            pk.x = cvt_pk_bf16(a[0], a[1]);
            pk.y = cvt_pk_bf16(a[2], a[3]);
            pk.z = cvt_pk_bf16(a[4], a[5]);
            pk.w = cvt_pk_bf16(a[6], a[7]);
        }
        *(uint4*)(h1c + off) = pk;
    }
    __syncthreads();

    // ---- conv2 via MFMA: wave w = px rows [4w,4w+4), both oc-halves ----
    const int lane  = tid & 63;
    const int w     = tid >> 6;
    const int lq    = lane >> 5;          // 0/1 -> k-half, also oc-local +4*lq
    const int lhalf = (lane >> 4) & 1;    // col>>4 within 32-col B tile
    const int pxl   = lane & 15;
    const int lq4   = lq << 4;

    const int baseNT0 = (w * 4 + lhalf) * 18 + pxl;       // NT=0: rows 4w,4w+1
    const int baseNT1 = baseNT0 + 36;                     // NT=1: rows 4w+2,4w+3

    const short8* a0p = (const short8*)W2r + (size_t)(g * 2) * 36 * 64 + lane;
    const short8* a1p = a0p + 36 * 64;

    f32x16 acc00 = {}, acc10 = {}, acc01 = {}, acc11 = {};  // acc[oh][NT]
    short8 A0[3], A1[3];
    A0[0] = a0p[0];  A1[0] = a1p[0];
    A0[1] = a0p[64]; A1[1] = a1p[64];

#pragma unroll
    for (int tap = 0; tap < 9; ++tap) {
        const int D = (tap / 3) * 18 + (tap % 3);
        int p0 = baseNT0 + D;
        int p1 = baseNT1 + D;
        int ad0 = (p0 << 7) + ((((p0 & 7) << 4)) ^ lq4);
        int ad1 = (p1 << 7) + ((((p1 & 7) << 4)) ^ lq4);
#pragma unroll
        for (int q = 0; q < 4; ++q) {
            const int kk = tap * 4 + q;
            if (kk + 2 < 36) {
                A0[(kk + 2) % 3] = a0p[(kk + 2) * 64];
                A1[(kk + 2) % 3] = a1p[(kk + 2) * 64];
            }
            short8 bf0 = *(const short8*)(h1c + (ad0 ^ (q << 5)));
            short8 bf1v = *(const short8*)(h1c + (ad1 ^ (q << 5)));
            acc00 = __builtin_amdgcn_mfma_f32_32x32x16_bf16(A0[kk % 3], bf0,  acc00, 0, 0, 0);
            acc10 = __builtin_amdgcn_mfma_f32_32x32x16_bf16(A1[kk % 3], bf0,  acc10, 0, 0, 0);
            acc01 = __builtin_amdgcn_mfma_f32_32x32x16_bf16(A0[kk % 3], bf1v, acc01, 0, 0, 0);
            acc11 = __builtin_amdgcn_mfma_f32_32x32x16_bf16(A1[kk % 3], bf1v, acc11, 0, 0, 0);
        }
    }

    // ---- epilogue: gelu(+b2), conv3 dot W3, half-wave reduce, direct store ----
    const float b3g = b3[g];
    float* outg = out + ((size_t)(n * NB + g) * 192 + y0) * 192 + x0;
#define EPI(ACC_O0, ACC_O1, NT)                                               \
    {                                                                         \
        float p = 0.f;                                                        \
        _Pragma("unroll")                                                     \
        for (int r = 0; r < 16; ++r) {                                        \
            int ocl = (r & 3) + ((r >> 2) << 3) + (lq << 2);                  \
            p += W3s[ocl]      * gelu_f(ACC_O0[r] + b2s[ocl]);                \
            p += W3s[32 + ocl] * gelu_f(ACC_O1[r] + b2s[32 + ocl]);           \
        }                                                                     \
        p += __shfl_xor(p, 32);                                               \
        if (lane < 32) {                                                      \
            int py = w * 4 + (NT) * 2 + (lane >> 4);                          \
            outg[py * 192 + (lane & 15)] = p + b3g;                           \
        }                                                                     \
    }
    EPI(acc00, acc10, 0)
    EPI(acc01, acc11, 1)
#undef EPI
}

// Cross-band fusion, in-place on `out` (each thread owns a full 31-channel pixel column).
__global__ __launch_bounds__(256) void fuse_kernel(
    const float* __restrict__ x,
    const float* __restrict__ Wf1, const float* __restrict__ bf1,
    const float* __restrict__ Wf2, const float* __restrict__ bf2,
    float* __restrict__ out)
{
    __shared__ float w1s[62 * 31], w2s[31 * 62], b1ss[62], b2ss[31];
    const int tid = threadIdx.x;
    for (int i = tid; i < 1922; i += 256) { w1s[i] = Wf1[i]; w2s[i] = Wf2[i]; }
    if (tid < 62) b1ss[tid] = bf1[tid];
    if (tid < 31) b2ss[tid] = bf2[tid];
    __syncthreads();

    int p = blockIdx.x * 256 + tid;          // 0..73727
    int nn = p / 36864, pix = p - nn * 36864;
    float* basep = out + (size_t)nn * NB * 36864 + pix;
    const float* xb = x + (size_t)nn * NB * 36864 + pix;

    float v[31];
#pragma unroll
    for (int c = 0; c < 31; ++c) v[c] = basep[(size_t)c * 36864];

    float fused[31];
#pragma unroll
    for (int c = 0; c < 31; ++c) fused[c] = b2ss[c];

    for (int j = 0; j < 62; ++j) {
        float a = b1ss[j];
#pragma unroll
        for (int c = 0; c < 31; ++c) a += w1s[j * 31 + c] * v[c];
        float fj = gelu_f(a);
#pragma unroll
        for (int c = 0; c < 31; ++c) fused[c] += w2s[c * 62 + j] * fj;
    }
#pragma unroll
    for (int c = 0; c < 31; ++c) basep[(size_t)c * 36864] = xb[(size_t)c * 36864] + fused[c];
}

extern "C" void kernel_launch(void* const* d_in, const int* in_sizes, int n_in,
                              void* d_out, int out_size, void* d_ws, size_t ws_size,
                              hipStream_t stream) {
    const float* x   = (const float*)d_in[0];
    const float* W1  = (const float*)d_in[1];
    const float* b1  = (const float*)d_in[2];
    const float* W2  = (const float*)d_in[3];
    const float* b2  = (const float*)d_in[4];
    const float* W3  = (const float*)d_in[5];
    const float* b3  = (const float*)d_in[6];
    const float* Wf1 = (const float*)d_in[7];
    const float* bf1 = (const float*)d_in[8];
    const float* Wf2 = (const float*)d_in[9];
    const float* bf2 = (const float*)d_in[10];
    float* out = (float*)d_out;
    unsigned short* W2r = (unsigned short*)d_ws;   // 1142784 bf16 = 2.29 MB

    const int TOT = NB * 2 * 36 * 512;
    hipLaunchKernelGGL(prep_w2, dim3((TOT + 255) / 256), dim3(256), 0, stream, W2, W2r);
    hipLaunchKernelGGL(band_kernel, dim3(144, NB, 2), dim3(256), 0, stream,
                       x, W1, b1, b2, W3, b3, W2r, out);
    hipLaunchKernelGGL(fuse_kernel, dim3(288), dim3(256), 0, stream,
                       x, Wf1, bf1, Wf2, bf2, out);
}

// Round 3
// 263.229 us; speedup vs baseline: 1.3768x; 1.2041x over previous
//
#include <hip/hip_runtime.h>
#include <hip/hip_bf16.h>

#define NB 31
#define PD 64

typedef __attribute__((ext_vector_type(8))) short short8;
typedef __attribute__((ext_vector_type(16))) float f32x16;

// 0-transcendental GELU: x * med3(0.5 + x*(a + b x^2 + c x^4), 0, 1)
__device__ __forceinline__ float gelu_f(float x) {
    float y = x * x;
    float p = __builtin_fmaf(y, __builtin_fmaf(y, 0.0042294f, -0.056913f), 0.395442f);
    float phi = __builtin_fmaf(x, p, 0.5f);
    asm("v_med3_f32 %0, %1, 0, 1.0" : "=v"(phi) : "v"(phi));
    return x * phi;
}

__device__ __forceinline__ unsigned int cvt_pk_bf16(float lo, float hi) {
    unsigned int r;
    asm("v_cvt_pk_bf16_f32 %0, %1, %2" : "=v"(r) : "v"(lo), "v"(hi));
    return r;
}

__device__ __forceinline__ unsigned short f2bf(float f) {
    unsigned int u = __float_as_uint(f);
    unsigned int r = (u + 0x7FFFu + ((u >> 16) & 1u)) >> 16;
    return (unsigned short)r;
}

// Reorder W2 (OIHW, fp32) -> MFMA A-fragment order (bf16):
// W2r[g][oh][kk][lane][j], oc = oh*32 + (lane&31), tap = kk>>2,
// ic = (kk&3)*16 + (lane>>5)*8 + j
__global__ void prep_w2(const float* __restrict__ W2, unsigned short* __restrict__ W2r) {
    int e = blockIdx.x * 256 + threadIdx.x;
    const int TOT = NB * 2 * 36 * 512;
    if (e >= TOT) return;
    int j  = e & 7;
    int l  = (e >> 3) & 63;
    int kk = (e >> 9) % 36;
    int gh = e / (36 * 512);
    int g  = gh >> 1, oh = gh & 1;
    int oc  = oh * 32 + (l & 31);
    int ic  = (kk & 3) * 16 + ((l >> 5) << 3) + j;
    int tap = kk >> 2;
    float v = W2[((g * 64 + oc) * 64 + ic) * 9 + tap];
    W2r[e] = f2bf(v);
}

// One block: (batch n, band g, 16x16 output tile). 256 threads = 4 waves.
__global__ __launch_bounds__(256, 3) void band_kernel(
    const float* __restrict__ x, const float* __restrict__ W1, const float* __restrict__ b1,
    const float* __restrict__ b2, const float* __restrict__ W3, const float* __restrict__ b3,
    const unsigned short* __restrict__ W2r, float* __restrict__ out)
{
    __shared__ float  xs[20 * 20];
    __shared__ float  W1s[9 * 64];
    __shared__ float  b1s[64], b2s[64], W3s[64];
    __shared__ short8 h1s8[324 * 8];   // 41472 B: [pos][64 ic] bf16, slot-swizzled

    const int tid = threadIdx.x;
    const int tx = blockIdx.x % 12, ty = blockIdx.x / 12;
    const int g = blockIdx.y, n = blockIdx.z;
    const int x0 = tx * 16, y0 = ty * 16;

    // ---- stage x tile (20x20, halo 2, zero-padded) ----
    const float* xg = x + (size_t)(n * NB + g) * 192 * 192;
    for (int i = tid; i < 400; i += 256) {
        int r = i / 20, c = i - r * 20;
        int gy = y0 + r - 2, gx = x0 + c - 2;
        float v = 0.f;
        if (gy >= 0 && gy < 192 && gx >= 0 && gx < 192) v = xg[gy * 192 + gx];
        xs[i] = v;
    }
    for (int i = tid; i < 576; i += 256) {
        int tap = i >> 6, ic = i & 63;
        W1s[i] = W1[(g * 64 + ic) * 9 + tap];
    }
    if (tid < 64) {
        b1s[tid] = b1[g * 64 + tid];
        b2s[tid] = b2[g * 64 + tid];
        W3s[tid] = W3[g * 64 + tid];
    }
    __syncthreads();

    // ---- conv1 + gelu -> h1s: thread owns fixed ic-chunk (tid&7), W1 in regs ----
    char* h1c = (char*)h1s8;
    {
        const int chunk = tid & 7;
        const int icb0 = chunk << 3;
        float w1r[72], b1r[8];
#pragma unroll
        for (int t = 0; t < 9; ++t)
#pragma unroll
            for (int u = 0; u < 8; ++u) w1r[t * 8 + u] = W1s[t * 64 + icb0 + u];
#pragma unroll
        for (int u = 0; u < 8; ++u) b1r[u] = b1s[icb0 + u];

        const int pbase = tid >> 3;
#pragma unroll
        for (int i = 0; i < 11; ++i) {
            int pos = pbase + (i << 5);
            if (pos >= 324) continue;
            int py = pos / 18, px = pos - py * 18;     // halo coords 0..17
            int gy = y0 + py - 1, gx = x0 + px - 1;
            int off = (pos << 7) + (((pos & 7) ^ chunk) << 4);
            uint4 pk = {0u, 0u, 0u, 0u};
            if (gy >= 0 && gy < 192 && gx >= 0 && gx < 192) {
                float xv[9];
#pragma unroll
                for (int t = 0; t < 9; ++t) xv[t] = xs[(py + t / 3) * 20 + (px + t % 3)];
                float a[8];
#pragma unroll
                for (int u = 0; u < 8; ++u) {
                    float s = b1r[u];
#pragma unroll
                    for (int t = 0; t < 9; ++t)
                        s = __builtin_fmaf(w1r[t * 8 + u], xv[t], s);
                    a[u] = gelu_f(s);
                }
                pk.x = cvt_pk_bf16(a[0], a[1]);
                pk.y = cvt_pk_bf16(a[2], a[3]);
                pk.z = cvt_pk_bf16(a[4], a[5]);
                pk.w = cvt_pk_bf16(a[6], a[7]);
            }
            *(uint4*)(h1c + off) = pk;
        }
    }
    __syncthreads();

    // ---- conv2 via MFMA: wave w = px rows [4w,4w+4), both oc-halves ----
    const int lane  = tid & 63;
    const int w     = tid >> 6;
    const int lq    = lane >> 5;
    const int lhalf = (lane >> 4) & 1;
    const int pxl   = lane & 15;
    const int lq4   = lq << 4;

    const int baseNT0 = (w * 4 + lhalf) * 18 + pxl;
    const int baseNT1 = baseNT0 + 36;

    const short8* a0p = (const short8*)W2r + (size_t)(g * 2) * 36 * 64 + lane;
    const short8* a1p = a0p + 36 * 64;

    f32x16 acc00 = {}, acc10 = {}, acc01 = {}, acc11 = {};
    short8 A0[3], A1[3];
    A0[0] = a0p[0];  A1[0] = a1p[0];
    A0[1] = a0p[64]; A1[1] = a1p[64];

#pragma unroll
    for (int tap = 0; tap < 9; ++tap) {
        const int D = (tap / 3) * 18 + (tap % 3);
        int p0 = baseNT0 + D;
        int p1 = baseNT1 + D;
        int ad0 = (p0 << 7) + ((((p0 & 7) << 4)) ^ lq4);
        int ad1 = (p1 << 7) + ((((p1 & 7) << 4)) ^ lq4);
#pragma unroll
        for (int q = 0; q < 4; ++q) {
            const int kk = tap * 4 + q;
            if (kk + 2 < 36) {
                A0[(kk + 2) % 3] = a0p[(kk + 2) * 64];
                A1[(kk + 2) % 3] = a1p[(kk + 2) * 64];
            }
            short8 bf0 = *(const short8*)(h1c + (ad0 ^ (q << 5)));
            short8 bf1v = *(const short8*)(h1c + (ad1 ^ (q << 5)));
            acc00 = __builtin_amdgcn_mfma_f32_32x32x16_bf16(A0[kk % 3], bf0,  acc00, 0, 0, 0);
            acc10 = __builtin_amdgcn_mfma_f32_32x32x16_bf16(A1[kk % 3], bf0,  acc10, 0, 0, 0);
            acc01 = __builtin_amdgcn_mfma_f32_32x32x16_bf16(A0[kk % 3], bf1v, acc01, 0, 0, 0);
            acc11 = __builtin_amdgcn_mfma_f32_32x32x16_bf16(A1[kk % 3], bf1v, acc11, 0, 0, 0);
        }
    }

    // ---- epilogue: gelu(+b2), conv3 dot W3, half-wave reduce, direct store ----
    const float b3g = b3[g];
    float* outg = out + ((size_t)(n * NB + g) * 192 + y0) * 192 + x0;
#define EPI(ACC_O0, ACC_O1, NT)                                               \
    {                                                                         \
        float p = 0.f;                                                        \
        _Pragma("unroll")                                                     \
        for (int r = 0; r < 16; ++r) {                                        \
            int ocl = (r & 3) + ((r >> 2) << 3) + (lq << 2);                  \
            p += W3s[ocl]      * gelu_f(ACC_O0[r] + b2s[ocl]);                \
            p += W3s[32 + ocl] * gelu_f(ACC_O1[r] + b2s[32 + ocl]);           \
        }                                                                     \
        p += __shfl_xor(p, 32);                                               \
        if (lane < 32) {                                                      \
            int py = w * 4 + (NT) * 2 + (lane >> 4);                          \
            outg[py * 192 + (lane & 15)] = p + b3g;                           \
        }                                                                     \
    }
    EPI(acc00, acc10, 0)
    EPI(acc01, acc11, 1)
#undef EPI
}

// Cross-band fusion, in-place on `out`. Weight indices are wave-uniform ->
// compiler emits s_load (K$/L2), no LDS staging needed.
__global__ __launch_bounds__(256) void fuse_kernel(
    const float* __restrict__ x,
    const float* __restrict__ Wf1, const float* __restrict__ bf1,
    const float* __restrict__ Wf2, const float* __restrict__ bf2,
    float* __restrict__ out)
{
    const int tid = threadIdx.x;
    int p = blockIdx.x * 256 + tid;          // 0..73727
    int nn = p / 36864, pix = p - nn * 36864;
    float* basep = out + (size_t)nn * NB * 36864 + pix;
    const float* xb = x + (size_t)nn * NB * 36864 + pix;

    float v[31];
#pragma unroll
    for (int c = 0; c < 31; ++c) v[c] = basep[(size_t)c * 36864];

    float fused[31];
#pragma unroll
    for (int c = 0; c < 31; ++c) fused[c] = bf2[c];

#pragma unroll 2
    for (int j = 0; j < 62; ++j) {
        float a = bf1[j];
#pragma unroll
        for (int c = 0; c < 31; ++c) a = __builtin_fmaf(Wf1[j * 31 + c], v[c], a);
        float fj = gelu_f(a);
#pragma unroll
        for (int c = 0; c < 31; ++c) fused[c] = __builtin_fmaf(Wf2[c * 62 + j], fj, fused[c]);
    }
#pragma unroll
    for (int c = 0; c < 31; ++c) basep[(size_t)c * 36864] = xb[(size_t)c * 36864] + fused[c];
}

extern "C" void kernel_launch(void* const* d_in, const int* in_sizes, int n_in,
                              void* d_out, int out_size, void* d_ws, size_t ws_size,
                              hipStream_t stream) {
    const float* x   = (const float*)d_in[0];
    const float* W1  = (const float*)d_in[1];
    const float* b1  = (const float*)d_in[2];
    const float* W2  = (const float*)d_in[3];
    const float* b2  = (const float*)d_in[4];
    const float* W3  = (const float*)d_in[5];
    const float* b3  = (const float*)d_in[6];
    const float* Wf1 = (const float*)d_in[7];
    const float* bf1 = (const float*)d_in[8];
    const float* Wf2 = (const float*)d_in[9];
    const float* bf2 = (const float*)d_in[10];
    float* out = (float*)d_out;
    unsigned short* W2r = (unsigned short*)d_ws;   // 1142784 bf16 = 2.29 MB

    const int TOT = NB * 2 * 36 * 512;
    hipLaunchKernelGGL(prep_w2, dim3((TOT + 255) / 256), dim3(256), 0, stream, W2, W2r);
    hipLaunchKernelGGL(band_kernel, dim3(144, NB, 2), dim3(256), 0, stream,
                       x, W1, b1, b2, W3, b3, W2r, out);
    hipLaunchKernelGGL(fuse_kernel, dim3(288), dim3(256), 0, stream,
                       x, Wf1, bf1, Wf2, bf2, out);
}

// Round 4
// 243.874 us; speedup vs baseline: 1.4860x; 1.0794x over previous
//
#include <hip/hip_runtime.h>
#include <hip/hip_bf16.h>

#define NB 31
#define PD 64

typedef __attribute__((ext_vector_type(8))) short short8;
typedef __attribute__((ext_vector_type(16))) float f32x16;

// 0-transcendental GELU: x * med3(0.5 + x*(a + b x^2 + c x^4), 0, 1)
__device__ __forceinline__ float gelu_f(float x) {
    float y = x * x;
    float p = __builtin_fmaf(y, __builtin_fmaf(y, 0.0042294f, -0.056913f), 0.395442f);
    float phi = __builtin_fmaf(x, p, 0.5f);
    asm("v_med3_f32 %0, %1, 0, 1.0" : "=v"(phi) : "v"(phi));
    return x * phi;
}

__device__ __forceinline__ unsigned int cvt_pk_bf16(float lo, float hi) {
    unsigned int r;
    asm("v_cvt_pk_bf16_f32 %0, %1, %2" : "=v"(r) : "v"(lo), "v"(hi));
    return r;
}

__device__ __forceinline__ unsigned short f2bf(float f) {
    unsigned int u = __float_as_uint(f);
    unsigned int r = (u + 0x7FFFu + ((u >> 16) & 1u)) >> 16;
    return (unsigned short)r;
}

// Reorder W2 (OIHW, fp32) -> MFMA A-fragment order (bf16):
// W2r[g][oh][kk][lane][j], oc = oh*32 + (lane&31), tap = kk>>2,
// ic = (kk&3)*16 + (lane>>5)*8 + j
__global__ void prep_w2(const float* __restrict__ W2, unsigned short* __restrict__ W2r) {
    int e = blockIdx.x * 256 + threadIdx.x;
    const int TOT = NB * 2 * 36 * 512;
    if (e >= TOT) return;
    int j  = e & 7;
    int l  = (e >> 3) & 63;
    int kk = (e >> 9) % 36;
    int gh = e / (36 * 512);
    int g  = gh >> 1, oh = gh & 1;
    int oc  = oh * 32 + (l & 31);
    int ic  = (kk & 3) * 16 + ((l >> 5) << 3) + j;
    int tap = kk >> 2;
    float v = W2[((g * 64 + oc) * 64 + ic) * 9 + tap];
    W2r[e] = f2bf(v);
}

// One block: (batch n, band g, 16x16 output tile). 256 threads = 4 waves.
// conv1 AND conv2 both via mfma_32x32x16_bf16; LDS holds only xs + h1.
__global__ __launch_bounds__(256, 3) void band_kernel(
    const float* __restrict__ x, const float* __restrict__ W1, const float* __restrict__ b1,
    const float* __restrict__ b2, const float* __restrict__ W3, const float* __restrict__ b3,
    const unsigned short* __restrict__ W2r, float* __restrict__ out)
{
    __shared__ float  xs[20 * 20];
    __shared__ short8 h1s8[324 * 8];   // 41472 B: [pos][64 ic] bf16, slot-swizzled

    const int tid = threadIdx.x;
    const int tx = blockIdx.x % 12, ty = blockIdx.x / 12;
    const int g = blockIdx.y, n = blockIdx.z;
    const int x0 = tx * 16, y0 = ty * 16;

    const int lane = tid & 63;
    const int w    = tid >> 6;
    const int hi   = lane >> 5;     // k-half for MFMA operands
    const int col  = lane & 31;

    // ---- stage x tile (20x20, halo 2, zero-padded) ----
    const float* xg = x + (size_t)(n * NB + g) * 192 * 192;
    for (int i = tid; i < 400; i += 256) {
        int r = i / 20, c = i - r * 20;
        int gy = y0 + r - 2, gx = x0 + c - 2;
        float v = 0.f;
        if (gy >= 0 && gy < 192 && gx >= 0 && gx < 192) v = xg[gy * 192 + gx];
        xs[i] = v;
    }

    // ---- conv1 A-frags from W1 (global, L1-cached): A[oc][k=tap], taps 9..15 = 0
    short8 a1[2];
#pragma unroll
    for (int oh = 0; oh < 2; ++oh) {
        const float* wp = W1 + (size_t)(g * 64 + oh * 32 + col) * 9;
        uint4 bw = {0u, 0u, 0u, 0u};
        if (hi == 0) {
            bw.x = cvt_pk_bf16(wp[0], wp[1]);
            bw.y = cvt_pk_bf16(wp[2], wp[3]);
            bw.z = cvt_pk_bf16(wp[4], wp[5]);
            bw.w = cvt_pk_bf16(wp[6], wp[7]);
        } else {
            bw.x = cvt_pk_bf16(wp[8], 0.f);
        }
        a1[oh] = __builtin_bit_cast(short8, bw);
    }
    // ---- b1 into regs: b1r[oh*16 + r] = b1[g*64 + oh*32 + (r&3) + 8*(r>>2) + 4*hi]
    float b1r[32];
    {
        const float* bp = b1 + g * 64 + 4 * hi;
#pragma unroll
        for (int oh = 0; oh < 2; ++oh)
#pragma unroll
            for (int s = 0; s < 4; ++s) {
                float4 q = *(const float4*)(bp + oh * 32 + 8 * s);
                b1r[oh * 16 + 4 * s + 0] = q.x;
                b1r[oh * 16 + 4 * s + 1] = q.y;
                b1r[oh * 16 + 4 * s + 2] = q.z;
                b1r[oh * 16 + 4 * s + 3] = q.w;
            }
    }
    __syncthreads();   // xs ready

    // ---- conv1 via MFMA: 11 tiles of 32 positions; wave w -> tiles w, w+4, w+8
    char* h1c = (char*)h1s8;
#pragma unroll
    for (int it = 0; it < 3; ++it) {
        const int t = w + 4 * it;
        if (t < 11) {
            int posr = t * 32 + col;
            int pos = posr < 324 ? posr : 323;
            int py = pos / 18, px = pos - py * 18;   // halo coords 0..17
            int gy = y0 + py - 1, gx = x0 + px - 1;
            unsigned int msk = (gy >= 0 && gy < 192 && gx >= 0 && gx < 192) ? 0xFFFFFFFFu : 0u;

            // B frag: B[k=tap][col=pos]; lanes<32: taps 0..7, lanes>=32: tap 8 + zeros
            uint4 bw = {0u, 0u, 0u, 0u};
            if (hi == 0) {
                float xv[8];
#pragma unroll
                for (int j2 = 0; j2 < 8; ++j2)
                    xv[j2] = xs[(py + j2 / 3) * 20 + px + (j2 % 3)];
                bw.x = cvt_pk_bf16(xv[0], xv[1]);
                bw.y = cvt_pk_bf16(xv[2], xv[3]);
                bw.z = cvt_pk_bf16(xv[4], xv[5]);
                bw.w = cvt_pk_bf16(xv[6], xv[7]);
            } else {
                bw.x = cvt_pk_bf16(xs[(py + 2) * 20 + px + 2], 0.f);
            }
            short8 bfrag = __builtin_bit_cast(short8, bw);

            f32x16 z = {};
            f32x16 c0 = __builtin_amdgcn_mfma_f32_32x32x16_bf16(a1[0], bfrag, z, 0, 0, 0);
            f32x16 c1 = __builtin_amdgcn_mfma_f32_32x32x16_bf16(a1[1], bfrag, z, 0, 0, 0);

            if (posr < 324) {
                const int pbase = (pos << 7) + (hi << 3);
#pragma unroll
                for (int oh = 0; oh < 2; ++oh) {
#pragma unroll
                    for (int s = 0; s < 4; ++s) {
                        float v0 = gelu_f((oh ? c1 : c0)[4 * s + 0] + b1r[oh * 16 + 4 * s + 0]);
                        float v1 = gelu_f((oh ? c1 : c0)[4 * s + 1] + b1r[oh * 16 + 4 * s + 1]);
                        float v2 = gelu_f((oh ? c1 : c0)[4 * s + 2] + b1r[oh * 16 + 4 * s + 2]);
                        float v3 = gelu_f((oh ? c1 : c0)[4 * s + 3] + b1r[oh * 16 + 4 * s + 3]);
                        uint2 dw;
                        dw.x = cvt_pk_bf16(v0, v1) & msk;
                        dw.y = cvt_pk_bf16(v2, v3) & msk;
                        int off = pbase + ((((pos & 7) ^ (oh * 4 + s))) << 4);
                        *(uint2*)(h1c + off) = dw;
                    }
                }
            }
        }
    }
    __syncthreads();

    // ---- conv2 via MFMA: wave w = px rows [4w,4w+4), both oc-halves ----
    const int lq    = hi;
    const int lhalf = (lane >> 4) & 1;
    const int pxl   = lane & 15;
    const int lq4   = lq << 4;

    const int baseNT0 = (w * 4 + lhalf) * 18 + pxl;
    const int baseNT1 = baseNT0 + 36;

    const short8* a0p = (const short8*)W2r + (size_t)(g * 2) * 36 * 64 + lane;
    const short8* a1p = a0p + 36 * 64;

    f32x16 acc00 = {}, acc10 = {}, acc01 = {}, acc11 = {};
    short8 A0[3], A1[3];
    A0[0] = a0p[0];  A1[0] = a1p[0];
    A0[1] = a0p[64]; A1[1] = a1p[64];

#pragma unroll
    for (int tap = 0; tap < 9; ++tap) {
        const int D = (tap / 3) * 18 + (tap % 3);
        int p0 = baseNT0 + D;
        int p1 = baseNT1 + D;
        int ad0 = (p0 << 7) + ((((p0 & 7) << 4)) ^ lq4);
        int ad1 = (p1 << 7) + ((((p1 & 7) << 4)) ^ lq4);
#pragma unroll
        for (int q = 0; q < 4; ++q) {
            const int kk = tap * 4 + q;
            if (kk + 2 < 36) {
                A0[(kk + 2) % 3] = a0p[(kk + 2) * 64];
                A1[(kk + 2) % 3] = a1p[(kk + 2) * 64];
            }
            short8 bf0 = *(const short8*)(h1c + (ad0 ^ (q << 5)));
            short8 bf1v = *(const short8*)(h1c + (ad1 ^ (q << 5)));
            acc00 = __builtin_amdgcn_mfma_f32_32x32x16_bf16(A0[kk % 3], bf0,  acc00, 0, 0, 0);
            acc10 = __builtin_amdgcn_mfma_f32_32x32x16_bf16(A1[kk % 3], bf0,  acc10, 0, 0, 0);
            acc01 = __builtin_amdgcn_mfma_f32_32x32x16_bf16(A0[kk % 3], bf1v, acc01, 0, 0, 0);
            acc11 = __builtin_amdgcn_mfma_f32_32x32x16_bf16(A1[kk % 3], bf1v, acc11, 0, 0, 0);
        }
    }

    // ---- epilogue: W3/b2 to regs (global, L1), gelu, conv3 dot, reduce, store
    float w3r[32], b2r[32];
    {
        const float* wp = W3 + g * 64 + 4 * lq;
        const float* bp = b2 + g * 64 + 4 * lq;
#pragma unroll
        for (int oh = 0; oh < 2; ++oh)
#pragma unroll
            for (int s = 0; s < 4; ++s) {
                float4 qa = *(const float4*)(wp + oh * 32 + 8 * s);
                float4 qb = *(const float4*)(bp + oh * 32 + 8 * s);
                w3r[oh * 16 + 4 * s + 0] = qa.x; w3r[oh * 16 + 4 * s + 1] = qa.y;
                w3r[oh * 16 + 4 * s + 2] = qa.z; w3r[oh * 16 + 4 * s + 3] = qa.w;
                b2r[oh * 16 + 4 * s + 0] = qb.x; b2r[oh * 16 + 4 * s + 1] = qb.y;
                b2r[oh * 16 + 4 * s + 2] = qb.z; b2r[oh * 16 + 4 * s + 3] = qb.w;
            }
    }
    const float b3g = b3[g];
    float* outg = out + ((size_t)(n * NB + g) * 192 + y0) * 192 + x0;
#define EPI(ACC_O0, ACC_O1, NT)                                               \
    {                                                                         \
        float p = 0.f;                                                        \
        _Pragma("unroll")                                                     \
        for (int r = 0; r < 16; ++r) {                                        \
            p += w3r[r]      * gelu_f(ACC_O0[r] + b2r[r]);                    \
            p += w3r[16 + r] * gelu_f(ACC_O1[r] + b2r[16 + r]);               \
        }                                                                     \
        p += __shfl_xor(p, 32);                                               \
        if (lane < 32) {                                                      \
            int py = w * 4 + (NT) * 2 + (lane >> 4);                          \
            outg[py * 192 + (lane & 15)] = p + b3g;                           \
        }                                                                     \
    }
    EPI(acc00, acc10, 0)
    EPI(acc01, acc11, 1)
#undef EPI
}

// Cross-band fusion, in-place on `out`. Weight indices are wave-uniform ->
// compiler emits s_load (K$/L2), no LDS staging needed.
__global__ __launch_bounds__(256) void fuse_kernel(
    const float* __restrict__ x,
    const float* __restrict__ Wf1, const float* __restrict__ bf1,
    const float* __restrict__ Wf2, const float* __restrict__ bf2,
    float* __restrict__ out)
{
    const int tid = threadIdx.x;
    int p = blockIdx.x * 256 + tid;          // 0..73727
    int nn = p / 36864, pix = p - nn * 36864;
    float* basep = out + (size_t)nn * NB * 36864 + pix;
    const float* xb = x + (size_t)nn * NB * 36864 + pix;

    float v[31];
#pragma unroll
    for (int c = 0; c < 31; ++c) v[c] = basep[(size_t)c * 36864];

    float fused[31];
#pragma unroll
    for (int c = 0; c < 31; ++c) fused[c] = bf2[c];

#pragma unroll 2
    for (int j = 0; j < 62; ++j) {
        float a = bf1[j];
#pragma unroll
        for (int c = 0; c < 31; ++c) a = __builtin_fmaf(Wf1[j * 31 + c], v[c], a);
        float fj = gelu_f(a);
#pragma unroll
        for (int c = 0; c < 31; ++c) fused[c] = __builtin_fmaf(Wf2[c * 62 + j], fj, fused[c]);
    }
#pragma unroll
    for (int c = 0; c < 31; ++c) basep[(size_t)c * 36864] = xb[(size_t)c * 36864] + fused[c];
}

extern "C" void kernel_launch(void* const* d_in, const int* in_sizes, int n_in,
                              void* d_out, int out_size, void* d_ws, size_t ws_size,
                              hipStream_t stream) {
    const float* x   = (const float*)d_in[0];
    const float* W1  = (const float*)d_in[1];
    const float* b1  = (const float*)d_in[2];
    const float* W2  = (const float*)d_in[3];
    const float* b2  = (const float*)d_in[4];
    const float* W3  = (const float*)d_in[5];
    const float* b3  = (const float*)d_in[6];
    const float* Wf1 = (const float*)d_in[7];
    const float* bf1 = (const float*)d_in[8];
    const float* Wf2 = (const float*)d_in[9];
    const float* bf2 = (const float*)d_in[10];
    float* out = (float*)d_out;
    unsigned short* W2r = (unsigned short*)d_ws;   // 1142784 bf16 = 2.29 MB

    const int TOT = NB * 2 * 36 * 512;
    hipLaunchKernelGGL(prep_w2, dim3((TOT + 255) / 256), dim3(256), 0, stream, W2, W2r);
    hipLaunchKernelGGL(band_kernel, dim3(144, NB, 2), dim3(256), 0, stream,
                       x, W1, b1, b2, W3, b3, W2r, out);
    hipLaunchKernelGGL(fuse_kernel, dim3(288), dim3(256), 0, stream,
                       x, Wf1, bf1, Wf2, bf2, out);
}